// Round 8
// baseline (527.294 us; speedup 1.0000x reference)
//
#include <hip/hip_runtime.h>
#include <hip/hip_fp16.h>
#include <string.h>

#ifndef __has_builtin
#define __has_builtin(x) 0
#endif
#if __has_builtin(__builtin_amdgcn_fdot2) && __has_builtin(__builtin_amdgcn_perm)
#define HAVE_FDOT2 1
#else
#define HAVE_FDOT2 0
#endif

namespace {
constexpr int kN = 50000;
constexpr int kD = 256;
constexpr int kPos = 32;
constexpr int kNeg = 20;
constexpr float kEps = 1e-15f;
constexpr int kSlots = kPos / 4 + kNeg / 4;  // 13 per 16-lane group

typedef _Float16 half2v __attribute__((ext_vector_type(2)));

// ---------- software fp8 e4m3fn <-> f32 via the f16 bit-correspondence ----------
// e4m3 value = f16(bits: s<<15 | (b&0x7f)<<7) * 2^8  (exact, incl. subnormals)
__device__ __forceinline__ uint enc1(float x) {
    const __half hh = __float2half(x * 0.00390625f);  // x * 2^-8, HW RNE
    unsigned short t;
    memcpy(&t, &hh, 2);
    const uint s = ((uint)t >> 8) & 0x80u;
    uint mag = (uint)t & 0x7fffu;
    mag = mag + 0x3fu + ((mag >> 7) & 1u);  // RNE 10->3 bit mantissa
    uint u = mag >> 7;
    if (u > 0x7eu) u = 0x7eu;
    return s | u;
}

__device__ __forceinline__ float dec_h(uint h) {
    __half hh;
    const unsigned short t = (unsigned short)h;
    memcpy(&hh, &t, 2);
    return __half2float(hh);
}

// scalar fallback decode: 4 fp8 bytes vs own[0..3] (own pre-scaled by 2^8, f32)
__device__ __forceinline__ void dq4(uint u, const float* o, float& d) {
    const float v0 = dec_h(((u << 8) & 0x8000u) | ((u << 7) & 0x3f80u));
    const float v1 = dec_h((u & 0x8000u) | ((u >> 1) & 0x3f80u));
    const float v2 = dec_h(((u >> 8) & 0x8000u) | ((u >> 9) & 0x3f80u));
    const float v3 = dec_h(((u >> 16) & 0x8000u) | ((u >> 17) & 0x3f80u));
    d = fmaf(v0, o[0], d);
    d = fmaf(v1, o[1], d);
    d = fmaf(v2, o[2], d);
    d = fmaf(v3, o[3], d);
}

#if HAVE_FDOT2
// packed decode: bytes (b0,b1) of u -> half2 {f16(b0), f16(b1)} (value*2^-8)
__device__ __forceinline__ half2v dq_pair(uint u, uint sel) {
    const uint r = __builtin_amdgcn_perm(0u, u, sel);  // b_lo<<8 | b_hi<<24
    const uint h = ((r >> 1) & 0x3f803f80u) | (r & 0x80008000u);
    half2v out;
    memcpy(&out, &h, 4);
    return out;
}
#endif

// ---------- fused fp32->fp8 convert + active-row compaction ----------
// Block b converts elems [b*2048, b*2048+2048) = rows 8b..8b+7; threads 0-7
// also compact those rows into list[] via atomic on acc[2].
__global__ __launch_bounds__(256) void convert_compact(const float* __restrict__ emb,
                                                       uint* __restrict__ tbl,
                                                       const int* __restrict__ rmask,
                                                       int* __restrict__ list,
                                                       float* __restrict__ acc) {
    const size_t i = ((size_t)blockIdx.x * 256 + threadIdx.x) * 8;
    const float4* src = reinterpret_cast<const float4*>(emb + i);
    const float4 a = src[0];
    const float4 b = src[1];
    uint2 o;
    o.x = enc1(a.x) | (enc1(a.y) << 8) | (enc1(a.z) << 16) | (enc1(a.w) << 24);
    o.y = enc1(b.x) | (enc1(b.y) << 8) | (enc1(b.z) << 16) | (enc1(b.w) << 24);
    reinterpret_cast<uint2*>(tbl)[i / 8] = o;

    if (threadIdx.x < 8) {
        const int n = blockIdx.x * 8 + threadIdx.x;
        if (n < kN && rmask[n]) {
            const int p = atomicAdd(reinterpret_cast<unsigned*>(&acc[2]), 1u);
            list[p] = n;
        }
    }
}

// One wave per ACTIVE row; wave = 4 groups x 16 lanes, one neighbor per group
// per slot, 13 slots, fully branch-free. fp8 row = 256 B; lane t loads one
// uint4 (elems 16t..16t+15); one wave instruction covers 4 rows x 256 B.
__global__ __launch_bounds__(256) void row_loss_fp8(
    const float* __restrict__ emb,
    const uchar* __restrict__ tblb,
    const int* __restrict__ nbr,
    const int* __restrict__ nbrm,
    const int* __restrict__ neg,
    const int* __restrict__ list,
    float* __restrict__ acc,
    float* __restrict__ out) {
    __shared__ float s_num[4];
    const int wave = threadIdx.x >> 6;
    const int lane = threadIdx.x & 63;
    const int g = lane >> 4;
    const int t = lane & 15;

    const int cnt_active = reinterpret_cast<const int*>(acc)[2];
    const int i = blockIdx.x * 4 + wave;
    float num = 0.f;

    if (i < cnt_active) {  // wave-uniform
        const int n = list[i];

        const float4* erow = reinterpret_cast<const float4*>(emb + (size_t)n * kD);
#if HAVE_FDOT2
        // own row as half2 pairs (elems 16t+2j, 16t+2j+1), pre-scaled by 2^8
        half2v own[8];
#pragma unroll
        for (int j = 0; j < 4; ++j) {
            const float4 f = erow[4 * t + j];
            own[2 * j] = half2v{(_Float16)(f.x * 256.f), (_Float16)(f.y * 256.f)};
            own[2 * j + 1] = half2v{(_Float16)(f.z * 256.f), (_Float16)(f.w * 256.f)};
        }
#else
        float own[16];
#pragma unroll
        for (int j = 0; j < 4; ++j) {
            const float4 f = erow[4 * t + j];
            own[4 * j + 0] = f.x * 256.f;
            own[4 * j + 1] = f.y * 256.f;
            own[4 * j + 2] = f.z * 256.f;
            own[4 * j + 3] = f.w * 256.f;
        }
#endif

        const int* nrow = nbr + (size_t)n * kPos;
        const int* mrow = nbrm + (size_t)n * kPos;
        const int* grow = neg + (size_t)n * kNeg;

        int idx[kSlots];
        float w[kPos / 4];
        float cnt = 0.f;
#pragma unroll
        for (int s = 0; s < kPos / 4; ++s) {
            idx[s] = nrow[s * 4 + g];
            const float mf = (float)mrow[s * 4 + g];
            w[s] = mf;
            cnt += mf;
        }
#pragma unroll
        for (int s = 0; s < kNeg / 4; ++s) idx[kPos / 4 + s] = grow[s * 4 + g];

        float pos_sum = 0.f, neg_sum = 0.f;
#pragma unroll
        for (int s = 0; s < kSlots; ++s) {
            const uint4 u =
                *reinterpret_cast<const uint4*>(tblb + (size_t)idx[s] * 256 + t * 16);
            float d = 0.f;
#if HAVE_FDOT2
            d = __builtin_amdgcn_fdot2(dq_pair(u.x, 0x010C000Cu), own[0], d, false);
            d = __builtin_amdgcn_fdot2(dq_pair(u.x, 0x030C020Cu), own[1], d, false);
            d = __builtin_amdgcn_fdot2(dq_pair(u.y, 0x010C000Cu), own[2], d, false);
            d = __builtin_amdgcn_fdot2(dq_pair(u.y, 0x030C020Cu), own[3], d, false);
            d = __builtin_amdgcn_fdot2(dq_pair(u.z, 0x010C000Cu), own[4], d, false);
            d = __builtin_amdgcn_fdot2(dq_pair(u.z, 0x030C020Cu), own[5], d, false);
            d = __builtin_amdgcn_fdot2(dq_pair(u.w, 0x010C000Cu), own[6], d, false);
            d = __builtin_amdgcn_fdot2(dq_pair(u.w, 0x030C020Cu), own[7], d, false);
#else
            dq4(u.x, own + 0, d);
            dq4(u.y, own + 4, d);
            dq4(u.z, own + 8, d);
            dq4(u.w, own + 12, d);
#endif
            d += __shfl_xor(d, 8);
            d += __shfl_xor(d, 4);
            d += __shfl_xor(d, 2);
            d += __shfl_xor(d, 1);
            const float sg = 1.f / (1.f + __expf(-d));
            if (s < kPos / 4) {  // compile-time branch (fully unrolled)
                pos_sum += -__logf(sg + kEps) * w[s];
            } else {
                neg_sum += -__logf(1.f - sg + kEps);
            }
        }

        pos_sum += __shfl_xor(pos_sum, 16);
        pos_sum += __shfl_xor(pos_sum, 32);
        neg_sum += __shfl_xor(neg_sum, 16);
        neg_sum += __shfl_xor(neg_sum, 32);
        cnt += __shfl_xor(cnt, 16);
        cnt += __shfl_xor(cnt, 32);

        if (cnt > 0.f) num = pos_sum / cnt + neg_sum / (float)kNeg;
        // cnt==0 -> NaN row in reference -> replaced by 0 -> contributes 0
    }

    if (lane == 0) s_num[wave] = num;
    __syncthreads();
    if (threadIdx.x == 0) {
        const float v = s_num[0] + s_num[1] + s_num[2] + s_num[3];
        if (v != 0.f) atomicAdd(&acc[0], v);
        __threadfence();
        const unsigned done = atomicAdd(reinterpret_cast<unsigned*>(&acc[3]), 1u);
        if (done == gridDim.x - 1) {
            const float a0 = atomicAdd(&acc[0], 0.f);  // coherent read-back
            out[0] = a0 / (float)cnt_active;
        }
    }
}

// ---------- fp32 direct fallback (only if d_ws too small) ----------
__global__ __launch_bounds__(256) void row_loss_f32(
    const float* __restrict__ emb,
    const int* __restrict__ nbr,
    const int* __restrict__ nbrm,
    const int* __restrict__ neg,
    const int* __restrict__ rmask,
    float* __restrict__ acc) {
    __shared__ float s_num[4];
    __shared__ float s_den[4];
    const int wave = threadIdx.x >> 6;
    const int lane = threadIdx.x & 63;
    const int n = blockIdx.x * 4 + wave;
    const int g = lane >> 4;
    const int t = lane & 15;

    const float4* erow = reinterpret_cast<const float4*>(emb + (size_t)n * kD);
    float4 own4[4];
#pragma unroll
    for (int j = 0; j < 4; ++j) own4[j] = erow[j * 16 + t];

    const int* nrow = nbr + (size_t)n * kPos;
    const int* mrow = nbrm + (size_t)n * kPos;
    const int* grow = neg + (size_t)n * kNeg;

    float pos_sum = 0.f, neg_sum = 0.f, cnt = 0.f;
#pragma unroll
    for (int it = 0; it < kPos / 4; ++it) {
        const int idx = nrow[it * 4 + g];
        const float mf = (float)mrow[it * 4 + g];
        cnt += mf;
        const float4* brow = reinterpret_cast<const float4*>(emb + (size_t)idx * kD);
        float d = 0.f;
#pragma unroll
        for (int j = 0; j < 4; ++j) {
            const float4 b = brow[j * 16 + t];
            const float4 a = own4[j];
            d += a.x * b.x + a.y * b.y + a.z * b.z + a.w * b.w;
        }
        d += __shfl_xor(d, 8);
        d += __shfl_xor(d, 4);
        d += __shfl_xor(d, 2);
        d += __shfl_xor(d, 1);
        const float s = 1.f / (1.f + __expf(-d));
        pos_sum += -__logf(s + kEps) * mf;
    }
#pragma unroll
    for (int it = 0; it < kNeg / 4; ++it) {
        const int idx = grow[it * 4 + g];
        const float4* brow = reinterpret_cast<const float4*>(emb + (size_t)idx * kD);
        float d = 0.f;
#pragma unroll
        for (int j = 0; j < 4; ++j) {
            const float4 b = brow[j * 16 + t];
            const float4 a = own4[j];
            d += a.x * b.x + a.y * b.y + a.z * b.z + a.w * b.w;
        }
        d += __shfl_xor(d, 8);
        d += __shfl_xor(d, 4);
        d += __shfl_xor(d, 2);
        d += __shfl_xor(d, 1);
        const float s = 1.f / (1.f + __expf(-d));
        neg_sum += -__logf(1.f - s + kEps);
    }

    pos_sum += __shfl_xor(pos_sum, 16);
    pos_sum += __shfl_xor(pos_sum, 32);
    neg_sum += __shfl_xor(neg_sum, 16);
    neg_sum += __shfl_xor(neg_sum, 32);
    cnt += __shfl_xor(cnt, 16);
    cnt += __shfl_xor(cnt, 32);

    float num = 0.f;
    if (cnt > 0.f) num = pos_sum / cnt + neg_sum / (float)kNeg;
    const float rmf = (float)rmask[n];

    if (lane == 0) {
        s_num[wave] = num * rmf;
        s_den[wave] = rmf;
    }
    __syncthreads();
    if (threadIdx.x == 0) {
        atomicAdd(&acc[0], s_num[0] + s_num[1] + s_num[2] + s_num[3]);
        atomicAdd(&acc[1], s_den[0] + s_den[1] + s_den[2] + s_den[3]);
    }
}

__global__ void finalize_f32(const float* __restrict__ acc, float* __restrict__ out) {
    out[0] = acc[0] / acc[1];
}
}  // namespace

extern "C" void kernel_launch(void* const* d_in, const int* in_sizes, int n_in,
                              void* d_out, int out_size, void* d_ws, size_t ws_size,
                              hipStream_t stream) {
    const float* emb = (const float*)d_in[0];
    const int* nbr = (const int*)d_in[1];
    const int* nbrm = (const int*)d_in[2];
    const int* neg = (const int*)d_in[3];
    const int* rmask = (const int*)d_in[4];
    float* acc = (float*)d_ws;  // [0]=num, [1]=den, [2]=active count, [3]=done ctr

    const size_t tbl_bytes = (size_t)kN * kD;  // 12.8 MB
    const size_t list_bytes = (size_t)kN * sizeof(int);
    if (ws_size >= 256 + tbl_bytes + list_bytes) {
        uint* tbl = (uint*)((char*)d_ws + 256);
        int* list = (int*)((char*)d_ws + 256 + tbl_bytes);
        hipMemsetAsync(acc, 0, 4 * sizeof(float), stream);
        convert_compact<<<kN * kD / 8 / 256, 256, 0, stream>>>(emb, tbl, rmask, list, acc);
        row_loss_fp8<<<(kN + 3) / 4, 256, 0, stream>>>(emb, (const uchar*)tbl, nbr, nbrm,
                                                       neg, list, acc, (float*)d_out);
    } else {
        hipMemsetAsync(acc, 0, 2 * sizeof(float), stream);
        row_loss_f32<<<kN / 4, 256, 0, stream>>>(emb, nbr, nbrm, neg, rmask, acc);
        finalize_f32<<<1, 1, 0, stream>>>(acc, (float*)d_out);
    }
}

// Round 10
// 506.779 us; speedup vs baseline: 1.0405x; 1.0405x over previous
//
#include <hip/hip_runtime.h>
#include <hip/hip_fp16.h>
#include <string.h>

namespace {
constexpr int kN = 50000;
constexpr int kD = 256;
constexpr int kPos = 32;
constexpr int kNeg = 20;
constexpr float kEps = 1e-15f;
constexpr int kSlots = kPos / 4 + kNeg / 4;  // 13 per 16-lane group

// ---------- software fp8 e4m3fn <-> f32 via the f16 bit-correspondence ----------
// e4m3 value = f16(bits: s<<15 | (b&0x7f)<<7) * 2^8  (exact, incl. subnormals)
__device__ __forceinline__ uint enc1(float x) {
    const __half hh = __float2half(x * 0.00390625f);  // x * 2^-8, HW RNE
    unsigned short t;
    memcpy(&t, &hh, 2);
    const uint s = ((uint)t >> 8) & 0x80u;
    uint mag = (uint)t & 0x7fffu;
    mag = mag + 0x3fu + ((mag >> 7) & 1u);  // RNE 10->3 bit mantissa
    uint u = mag >> 7;
    if (u > 0x7eu) u = 0x7eu;
    return s | u;
}

__device__ __forceinline__ float dec_h(uint h) {
    __half hh;
    const unsigned short t = (unsigned short)h;
    memcpy(&hh, &t, 2);
    return __half2float(hh);
}

// decode 4 fp8 bytes of u, fma against o[0..3] (own pre-scaled by 2^8, f32).
// Proven in R6/R7 (absmax 0.0; 95 us in R7's schedule).
__device__ __forceinline__ void dq4(uint u, const float* o, float& d) {
    const float v0 = dec_h(((u << 8) & 0x8000u) | ((u << 7) & 0x3f80u));
    const float v1 = dec_h((u & 0x8000u) | ((u >> 1) & 0x3f80u));
    const float v2 = dec_h(((u >> 8) & 0x8000u) | ((u >> 9) & 0x3f80u));
    const float v3 = dec_h(((u >> 16) & 0x8000u) | ((u >> 17) & 0x3f80u));
    d = fmaf(v0, o[0], d);
    d = fmaf(v1, o[1], d);
    d = fmaf(v2, o[2], d);
    d = fmaf(v3, o[3], d);
}

// ---------- fused fp32->fp8 convert + active-row compaction (ran in R8) ----------
// Block b converts rows 8b..8b+7; threads 0-7 compact those rows into list[].
__global__ __launch_bounds__(256) void convert_compact(const float* __restrict__ emb,
                                                       uint* __restrict__ tbl,
                                                       const int* __restrict__ rmask,
                                                       int* __restrict__ list,
                                                       float* __restrict__ acc) {
    const size_t i = ((size_t)blockIdx.x * 256 + threadIdx.x) * 8;
    const float4* src = reinterpret_cast<const float4*>(emb + i);
    const float4 a = src[0];
    const float4 b = src[1];
    uint2 o;
    o.x = enc1(a.x) | (enc1(a.y) << 8) | (enc1(a.z) << 16) | (enc1(a.w) << 24);
    o.y = enc1(b.x) | (enc1(b.y) << 8) | (enc1(b.z) << 16) | (enc1(b.w) << 24);
    reinterpret_cast<uint2*>(tbl)[i / 8] = o;

    if (threadIdx.x < 8) {
        const int n = blockIdx.x * 8 + threadIdx.x;
        if (n < kN && rmask[n]) {
            const int p = atomicAdd(reinterpret_cast<unsigned*>(&acc[2]), 1u);
            list[p] = n;
        }
    }
}

// One wave per ACTIVE row; wave = 4 groups x 16 lanes, one neighbor per group
// per slot, 13 slots, branch-free. EXACT R7 inner loop (dq4 math, gather
// issued per-slot inside the fully-unrolled loop — the schedule that measured
// 95 us / VALUBusy 70%). R9's register-array gather hoist crashed; reverted.
__global__ __launch_bounds__(256) void row_loss_fp8(
    const float* __restrict__ emb,
    const uchar* __restrict__ tblb,
    const int* __restrict__ nbr,
    const int* __restrict__ nbrm,
    const int* __restrict__ neg,
    const int* __restrict__ list,
    float* __restrict__ acc,
    float* __restrict__ out) {
    __shared__ float s_num[4];
    const int wave = threadIdx.x >> 6;
    const int lane = threadIdx.x & 63;
    const int g = lane >> 4;
    const int t = lane & 15;

    const int cnt_active = reinterpret_cast<const int*>(acc)[2];
    const int i = blockIdx.x * 4 + wave;
    float num = 0.f;

    if (i < cnt_active) {  // wave-uniform
        const int n = list[i];

        // own row fp32 (exact), elems 16t..16t+15, pre-scaled by 2^8 to fold
        // the fp8->f16 decode scale.
        const float4* erow = reinterpret_cast<const float4*>(emb + (size_t)n * kD);
        float own[16];
#pragma unroll
        for (int j = 0; j < 4; ++j) {
            const float4 f = erow[4 * t + j];
            own[4 * j + 0] = f.x * 256.f;
            own[4 * j + 1] = f.y * 256.f;
            own[4 * j + 2] = f.z * 256.f;
            own[4 * j + 3] = f.w * 256.f;
        }

        const int* nrow = nbr + (size_t)n * kPos;
        const int* mrow = nbrm + (size_t)n * kPos;
        const int* grow = neg + (size_t)n * kNeg;

        int idx[kSlots];
        float w[kPos / 4];
        float cnt = 0.f;
#pragma unroll
        for (int s = 0; s < kPos / 4; ++s) {
            idx[s] = nrow[s * 4 + g];
            const float mf = (float)mrow[s * 4 + g];
            w[s] = mf;
            cnt += mf;
        }
#pragma unroll
        for (int s = 0; s < kNeg / 4; ++s) idx[kPos / 4 + s] = grow[s * 4 + g];

        float pos_sum = 0.f, neg_sum = 0.f;
#pragma unroll
        for (int s = 0; s < kSlots; ++s) {
            const uint4 u =
                *reinterpret_cast<const uint4*>(tblb + (size_t)idx[s] * 256 + t * 16);
            float d = 0.f;
            dq4(u.x, own + 0, d);
            dq4(u.y, own + 4, d);
            dq4(u.z, own + 8, d);
            dq4(u.w, own + 12, d);
            d += __shfl_xor(d, 8);
            d += __shfl_xor(d, 4);
            d += __shfl_xor(d, 2);
            d += __shfl_xor(d, 1);
            const float sg = 1.f / (1.f + __expf(-d));
            if (s < kPos / 4) {  // compile-time branch (fully unrolled)
                pos_sum += -__logf(sg + kEps) * w[s];
            } else {
                neg_sum += -__logf(1.f - sg + kEps);
            }
        }

        pos_sum += __shfl_xor(pos_sum, 16);
        pos_sum += __shfl_xor(pos_sum, 32);
        neg_sum += __shfl_xor(neg_sum, 16);
        neg_sum += __shfl_xor(neg_sum, 32);
        cnt += __shfl_xor(cnt, 16);
        cnt += __shfl_xor(cnt, 32);

        if (cnt > 0.f) num = pos_sum / cnt + neg_sum / (float)kNeg;
        // cnt==0 -> NaN row in reference -> replaced by 0 -> contributes 0
    }

    if (lane == 0) s_num[wave] = num;
    __syncthreads();
    if (threadIdx.x == 0) {
        const float v = s_num[0] + s_num[1] + s_num[2] + s_num[3];
        if (v != 0.f) atomicAdd(&acc[0], v);
        __threadfence();
        const unsigned done = atomicAdd(reinterpret_cast<unsigned*>(&acc[3]), 1u);
        if (done == gridDim.x - 1) {
            const float a0 = atomicAdd(&acc[0], 0.f);  // coherent read-back
            out[0] = a0 / (float)cnt_active;
        }
    }
}

// ---------- fp32 direct fallback (only if d_ws too small) ----------
__global__ __launch_bounds__(256) void row_loss_f32(
    const float* __restrict__ emb,
    const int* __restrict__ nbr,
    const int* __restrict__ nbrm,
    const int* __restrict__ neg,
    const int* __restrict__ rmask,
    float* __restrict__ acc) {
    __shared__ float s_num[4];
    __shared__ float s_den[4];
    const int wave = threadIdx.x >> 6;
    const int lane = threadIdx.x & 63;
    const int n = blockIdx.x * 4 + wave;
    const int g = lane >> 4;
    const int t = lane & 15;

    const float4* erow = reinterpret_cast<const float4*>(emb + (size_t)n * kD);
    float4 own4[4];
#pragma unroll
    for (int j = 0; j < 4; ++j) own4[j] = erow[j * 16 + t];

    const int* nrow = nbr + (size_t)n * kPos;
    const int* mrow = nbrm + (size_t)n * kPos;
    const int* grow = neg + (size_t)n * kNeg;

    float pos_sum = 0.f, neg_sum = 0.f, cnt = 0.f;
#pragma unroll
    for (int it = 0; it < kPos / 4; ++it) {
        const int idx = nrow[it * 4 + g];
        const float mf = (float)mrow[it * 4 + g];
        cnt += mf;
        const float4* brow = reinterpret_cast<const float4*>(emb + (size_t)idx * kD);
        float d = 0.f;
#pragma unroll
        for (int j = 0; j < 4; ++j) {
            const float4 b = brow[j * 16 + t];
            const float4 a = own4[j];
            d += a.x * b.x + a.y * b.y + a.z * b.z + a.w * b.w;
        }
        d += __shfl_xor(d, 8);
        d += __shfl_xor(d, 4);
        d += __shfl_xor(d, 2);
        d += __shfl_xor(d, 1);
        const float s = 1.f / (1.f + __expf(-d));
        pos_sum += -__logf(s + kEps) * mf;
    }
#pragma unroll
    for (int it = 0; it < kNeg / 4; ++it) {
        const int idx = grow[it * 4 + g];
        const float4* brow = reinterpret_cast<const float4*>(emb + (size_t)idx * kD);
        float d = 0.f;
#pragma unroll
        for (int j = 0; j < 4; ++j) {
            const float4 b = brow[j * 16 + t];
            const float4 a = own4[j];
            d += a.x * b.x + a.y * b.y + a.z * b.z + a.w * b.w;
        }
        d += __shfl_xor(d, 8);
        d += __shfl_xor(d, 4);
        d += __shfl_xor(d, 2);
        d += __shfl_xor(d, 1);
        const float s = 1.f / (1.f + __expf(-d));
        neg_sum += -__logf(1.f - s + kEps);
    }

    pos_sum += __shfl_xor(pos_sum, 16);
    pos_sum += __shfl_xor(pos_sum, 32);
    neg_sum += __shfl_xor(neg_sum, 16);
    neg_sum += __shfl_xor(neg_sum, 32);
    cnt += __shfl_xor(cnt, 16);
    cnt += __shfl_xor(cnt, 32);

    float num = 0.f;
    if (cnt > 0.f) num = pos_sum / cnt + neg_sum / (float)kNeg;
    const float rmf = (float)rmask[n];

    if (lane == 0) {
        s_num[wave] = num * rmf;
        s_den[wave] = rmf;
    }
    __syncthreads();
    if (threadIdx.x == 0) {
        atomicAdd(&acc[0], s_num[0] + s_num[1] + s_num[2] + s_num[3]);
        atomicAdd(&acc[1], s_den[0] + s_den[1] + s_den[2] + s_den[3]);
    }
}

__global__ void finalize_f32(const float* __restrict__ acc, float* __restrict__ out) {
    out[0] = acc[0] / acc[1];
}
}  // namespace

extern "C" void kernel_launch(void* const* d_in, const int* in_sizes, int n_in,
                              void* d_out, int out_size, void* d_ws, size_t ws_size,
                              hipStream_t stream) {
    const float* emb = (const float*)d_in[0];
    const int* nbr = (const int*)d_in[1];
    const int* nbrm = (const int*)d_in[2];
    const int* neg = (const int*)d_in[3];
    const int* rmask = (const int*)d_in[4];
    float* acc = (float*)d_ws;  // [0]=num, [1]=den, [2]=active count, [3]=done ctr

    const size_t tbl_bytes = (size_t)kN * kD;  // 12.8 MB
    const size_t list_bytes = (size_t)kN * sizeof(int);
    if (ws_size >= 256 + tbl_bytes + list_bytes) {
        uint* tbl = (uint*)((char*)d_ws + 256);
        int* list = (int*)((char*)d_ws + 256 + tbl_bytes);
        hipMemsetAsync(acc, 0, 4 * sizeof(float), stream);
        convert_compact<<<kN * kD / 8 / 256, 256, 0, stream>>>(emb, tbl, rmask, list, acc);
        row_loss_fp8<<<(kN + 3) / 4, 256, 0, stream>>>(emb, (const uchar*)tbl, nbr, nbrm,
                                                       neg, list, acc, (float*)d_out);
    } else {
        hipMemsetAsync(acc, 0, 2 * sizeof(float), stream);
        row_loss_f32<<<kN / 4, 256, 0, stream>>>(emb, nbr, nbrm, neg, rmask, acc);
        finalize_f32<<<1, 1, 0, stream>>>(acc, (float*)d_out);
    }
}

// Round 11
// 257.735 us; speedup vs baseline: 2.0459x; 1.9663x over previous
//
#include <hip/hip_runtime.h>
#include <hip/hip_fp16.h>
#include <string.h>

namespace {
constexpr int kN = 50000;
constexpr int kD = 256;
constexpr int kPos = 32;
constexpr int kNeg = 20;
constexpr float kEps = 1e-15f;
constexpr int kSlots = kPos / 4 + kNeg / 4;  // 13 per 16-lane group

// ---------- software fp8 e4m3fn <-> f32 via the f16 bit-correspondence ----------
// e4m3 value = f16(bits: s<<15 | (b&0x7f)<<7) * 2^8  (exact, incl. subnormals)
__device__ __forceinline__ uint enc1(float x) {
    const __half hh = __float2half(x * 0.00390625f);  // x * 2^-8, HW RNE
    unsigned short t;
    memcpy(&t, &hh, 2);
    const uint s = ((uint)t >> 8) & 0x80u;
    uint mag = (uint)t & 0x7fffu;
    mag = mag + 0x3fu + ((mag >> 7) & 1u);  // RNE 10->3 bit mantissa
    uint u = mag >> 7;
    if (u > 0x7eu) u = 0x7eu;
    return s | u;
}

__device__ __forceinline__ float dec_h(uint h) {
    __half hh;
    const unsigned short t = (unsigned short)h;
    memcpy(&hh, &t, 2);
    return __half2float(hh);
}

// decode 4 fp8 bytes of u, fma against o[0..3] (own pre-scaled by 2^8, f32).
// Proven in R6/R7 (absmax 0.0; 95 us in R7).
__device__ __forceinline__ void dq4(uint u, const float* o, float& d) {
    const float v0 = dec_h(((u << 8) & 0x8000u) | ((u << 7) & 0x3f80u));
    const float v1 = dec_h((u & 0x8000u) | ((u >> 1) & 0x3f80u));
    const float v2 = dec_h(((u >> 8) & 0x8000u) | ((u >> 9) & 0x3f80u));
    const float v3 = dec_h(((u >> 16) & 0x8000u) | ((u >> 17) & 0x3f80u));
    d = fmaf(v0, o[0], d);
    d = fmaf(v1, o[1], d);
    d = fmaf(v2, o[2], d);
    d = fmaf(v3, o[3], d);
}

// ---------- fused fp32->fp8 convert + active-row compaction ----------
// Block b converts rows 8b..8b+7; threads 0-7 compact those rows into list[].
// Runs BEFORE row_loss, so it cannot perturb row_loss's cache state.
__global__ __launch_bounds__(256) void convert_compact(const float* __restrict__ emb,
                                                       uint* __restrict__ tbl,
                                                       const int* __restrict__ rmask,
                                                       int* __restrict__ list,
                                                       float* __restrict__ acc) {
    const size_t i = ((size_t)blockIdx.x * 256 + threadIdx.x) * 8;
    const float4* src = reinterpret_cast<const float4*>(emb + i);
    const float4 a = src[0];
    const float4 b = src[1];
    uint2 o;
    o.x = enc1(a.x) | (enc1(a.y) << 8) | (enc1(a.z) << 16) | (enc1(a.w) << 24);
    o.y = enc1(b.x) | (enc1(b.y) << 8) | (enc1(b.z) << 16) | (enc1(b.w) << 24);
    reinterpret_cast<uint2*>(tbl)[i / 8] = o;

    if (threadIdx.x < 8) {
        const int n = blockIdx.x * 8 + threadIdx.x;
        if (n < kN && rmask[n]) {
            const int p = atomicAdd(reinterpret_cast<unsigned*>(&acc[2]), 1u);
            list[p] = n;
        }
    }
}

// One wave per ACTIVE row; wave = 4 groups x 16 lanes, one neighbor per group
// per slot, 13 slots, branch-free. EXACT R7 inner loop AND epilogue.
// NOTE: no __threadfence / done-counter here — the per-block device-scope
// fence (emits L2 invalidate on gfx950) destroyed the gather table's L2
// residency in R3/R8/R10 (355-518 us vs 95 us, same FETCH_SIZE).
__global__ __launch_bounds__(256) void row_loss_fp8(
    const float* __restrict__ emb,
    const uchar* __restrict__ tblb,
    const int* __restrict__ nbr,
    const int* __restrict__ nbrm,
    const int* __restrict__ neg,
    const int* __restrict__ list,
    float* __restrict__ acc) {
    __shared__ float s_num[4];
    const int wave = threadIdx.x >> 6;
    const int lane = threadIdx.x & 63;
    const int g = lane >> 4;
    const int t = lane & 15;

    const int cnt_active = reinterpret_cast<const int*>(acc)[2];
    const int i = blockIdx.x * 4 + wave;
    float num = 0.f;

    if (i < cnt_active) {  // wave-uniform
        const int n = list[i];

        // own row fp32 (exact), elems 16t..16t+15, pre-scaled by 2^8 to fold
        // the fp8->f16 decode scale.
        const float4* erow = reinterpret_cast<const float4*>(emb + (size_t)n * kD);
        float own[16];
#pragma unroll
        for (int j = 0; j < 4; ++j) {
            const float4 f = erow[4 * t + j];
            own[4 * j + 0] = f.x * 256.f;
            own[4 * j + 1] = f.y * 256.f;
            own[4 * j + 2] = f.z * 256.f;
            own[4 * j + 3] = f.w * 256.f;
        }

        const int* nrow = nbr + (size_t)n * kPos;
        const int* mrow = nbrm + (size_t)n * kPos;
        const int* grow = neg + (size_t)n * kNeg;

        int idx[kSlots];
        float w[kPos / 4];
        float cnt = 0.f;
#pragma unroll
        for (int s = 0; s < kPos / 4; ++s) {
            idx[s] = nrow[s * 4 + g];
            const float mf = (float)mrow[s * 4 + g];
            w[s] = mf;
            cnt += mf;
        }
#pragma unroll
        for (int s = 0; s < kNeg / 4; ++s) idx[kPos / 4 + s] = grow[s * 4 + g];

        float pos_sum = 0.f, neg_sum = 0.f;
#pragma unroll
        for (int s = 0; s < kSlots; ++s) {
            const uint4 u =
                *reinterpret_cast<const uint4*>(tblb + (size_t)idx[s] * 256 + t * 16);
            float d = 0.f;
            dq4(u.x, own + 0, d);
            dq4(u.y, own + 4, d);
            dq4(u.z, own + 8, d);
            dq4(u.w, own + 12, d);
            d += __shfl_xor(d, 8);
            d += __shfl_xor(d, 4);
            d += __shfl_xor(d, 2);
            d += __shfl_xor(d, 1);
            const float sg = 1.f / (1.f + __expf(-d));
            if (s < kPos / 4) {  // compile-time branch (fully unrolled)
                pos_sum += -__logf(sg + kEps) * w[s];
            } else {
                neg_sum += -__logf(1.f - sg + kEps);
            }
        }

        pos_sum += __shfl_xor(pos_sum, 16);
        pos_sum += __shfl_xor(pos_sum, 32);
        neg_sum += __shfl_xor(neg_sum, 16);
        neg_sum += __shfl_xor(neg_sum, 32);
        cnt += __shfl_xor(cnt, 16);
        cnt += __shfl_xor(cnt, 32);

        if (cnt > 0.f) num = pos_sum / cnt + neg_sum / (float)kNeg;
        // cnt==0 -> NaN row in reference -> replaced by 0 -> contributes 0
    }

    if (lane == 0) s_num[wave] = num;
    __syncthreads();
    if (threadIdx.x == 0) {
        const float v = s_num[0] + s_num[1] + s_num[2] + s_num[3];
        if (v != 0.f) atomicAdd(&acc[0], v);
    }
}

__global__ void finalize_kernel(const float* __restrict__ acc, float* __restrict__ out) {
    out[0] = acc[0] / (float)reinterpret_cast<const int*>(acc)[2];
}

// ---------- fp32 direct fallback (only if d_ws too small) ----------
__global__ __launch_bounds__(256) void row_loss_f32(
    const float* __restrict__ emb,
    const int* __restrict__ nbr,
    const int* __restrict__ nbrm,
    const int* __restrict__ neg,
    const int* __restrict__ rmask,
    float* __restrict__ acc) {
    __shared__ float s_num[4];
    __shared__ float s_den[4];
    const int wave = threadIdx.x >> 6;
    const int lane = threadIdx.x & 63;
    const int n = blockIdx.x * 4 + wave;
    const int g = lane >> 4;
    const int t = lane & 15;

    const float4* erow = reinterpret_cast<const float4*>(emb + (size_t)n * kD);
    float4 own4[4];
#pragma unroll
    for (int j = 0; j < 4; ++j) own4[j] = erow[j * 16 + t];

    const int* nrow = nbr + (size_t)n * kPos;
    const int* mrow = nbrm + (size_t)n * kPos;
    const int* grow = neg + (size_t)n * kNeg;

    float pos_sum = 0.f, neg_sum = 0.f, cnt = 0.f;
#pragma unroll
    for (int it = 0; it < kPos / 4; ++it) {
        const int idx = nrow[it * 4 + g];
        const float mf = (float)mrow[it * 4 + g];
        cnt += mf;
        const float4* brow = reinterpret_cast<const float4*>(emb + (size_t)idx * kD);
        float d = 0.f;
#pragma unroll
        for (int j = 0; j < 4; ++j) {
            const float4 b = brow[j * 16 + t];
            const float4 a = own4[j];
            d += a.x * b.x + a.y * b.y + a.z * b.z + a.w * b.w;
        }
        d += __shfl_xor(d, 8);
        d += __shfl_xor(d, 4);
        d += __shfl_xor(d, 2);
        d += __shfl_xor(d, 1);
        const float s = 1.f / (1.f + __expf(-d));
        pos_sum += -__logf(s + kEps) * mf;
    }
#pragma unroll
    for (int it = 0; it < kNeg / 4; ++it) {
        const int idx = grow[it * 4 + g];
        const float4* brow = reinterpret_cast<const float4*>(emb + (size_t)idx * kD);
        float d = 0.f;
#pragma unroll
        for (int j = 0; j < 4; ++j) {
            const float4 b = brow[j * 16 + t];
            const float4 a = own4[j];
            d += a.x * b.x + a.y * b.y + a.z * b.z + a.w * b.w;
        }
        d += __shfl_xor(d, 8);
        d += __shfl_xor(d, 4);
        d += __shfl_xor(d, 2);
        d += __shfl_xor(d, 1);
        const float s = 1.f / (1.f + __expf(-d));
        neg_sum += -__logf(1.f - s + kEps);
    }

    pos_sum += __shfl_xor(pos_sum, 16);
    pos_sum += __shfl_xor(pos_sum, 32);
    neg_sum += __shfl_xor(neg_sum, 16);
    neg_sum += __shfl_xor(neg_sum, 32);
    cnt += __shfl_xor(cnt, 16);
    cnt += __shfl_xor(cnt, 32);

    float num = 0.f;
    if (cnt > 0.f) num = pos_sum / cnt + neg_sum / (float)kNeg;
    const float rmf = (float)rmask[n];

    if (lane == 0) {
        s_num[wave] = num * rmf;
        s_den[wave] = rmf;
    }
    __syncthreads();
    if (threadIdx.x == 0) {
        atomicAdd(&acc[0], s_num[0] + s_num[1] + s_num[2] + s_num[3]);
        atomicAdd(&acc[1], s_den[0] + s_den[1] + s_den[2] + s_den[3]);
    }
}

__global__ void finalize_f32(const float* __restrict__ acc, float* __restrict__ out) {
    out[0] = acc[0] / acc[1];
}
}  // namespace

extern "C" void kernel_launch(void* const* d_in, const int* in_sizes, int n_in,
                              void* d_out, int out_size, void* d_ws, size_t ws_size,
                              hipStream_t stream) {
    const float* emb = (const float*)d_in[0];
    const int* nbr = (const int*)d_in[1];
    const int* nbrm = (const int*)d_in[2];
    const int* neg = (const int*)d_in[3];
    const int* rmask = (const int*)d_in[4];
    float* acc = (float*)d_ws;  // [0]=num, [1]=den, [2]=active count

    const size_t tbl_bytes = (size_t)kN * kD;  // 12.8 MB
    const size_t list_bytes = (size_t)kN * sizeof(int);
    if (ws_size >= 256 + tbl_bytes + list_bytes) {
        uint* tbl = (uint*)((char*)d_ws + 256);
        int* list = (int*)((char*)d_ws + 256 + tbl_bytes);
        hipMemsetAsync(acc, 0, 4 * sizeof(float), stream);
        convert_compact<<<kN * kD / 8 / 256, 256, 0, stream>>>(emb, tbl, rmask, list, acc);
        row_loss_fp8<<<(kN + 3) / 4, 256, 0, stream>>>(emb, (const uchar*)tbl, nbr, nbrm,
                                                       neg, list, acc);
        finalize_kernel<<<1, 1, 0, stream>>>(acc, (float*)d_out);
    } else {
        hipMemsetAsync(acc, 0, 2 * sizeof(float), stream);
        row_loss_f32<<<kN / 4, 256, 0, stream>>>(emb, nbr, nbrm, neg, rmask, acc);
        finalize_f32<<<1, 1, 0, stream>>>(acc, (float*)d_out);
    }
}